// Round 8
// baseline (19.298 us; speedup 1.0000x reference)
//
#include <hip/hip_runtime.h>
#include <math.h>

// RDF with Gaussian smearing, N=512 points, 400 bins. Two dispatches:
// K1: 128 blocks x 512 thr histogram unordered pairs into LDS (Gaussian via
//     multiplicative recurrence, fixed 9-bin unrolled window), store partials.
// K2: 1 block reduces 128 partials, normalizes, writes count/bins/rdf.
// out layout: count[0..399], bins[400..800] (401 vals), rdf[801..1200]
#define NBINS 400
#define NPTS  512
#define RMAXF 13.635f
#define BOXF  (2.0f * RMAXF)
#define NBLK  128
#define TPB   512

__global__ __launch_bounds__(512) void rdf_hist(const float* __restrict__ pos,
                                                float* __restrict__ part) {
    __shared__ float hist[NBINS];
    const int tid = threadIdx.x;
    for (int b = tid; b < NBINS; b += TPB) hist[b] = 0.0f;
    __syncthreads();

    const float inv_w = 399.0f / RMAXF;     // 1/width
    // E(b)=exp(-0.5*u^2), u = c-b (bin-width units). Recurrence along b:
    //   E <- E*F,  F <- F*e^-1,  with E0=exp2(-0.5*log2e*u0^2),
    //   F0=exp2(log2e*(u0-0.5)).  Exact identity; f32 rounding ~8 ulp.
    const float C2E = -0.72134752f;         // -0.5*log2(e)
    const float C2F = 1.44269504f;          // log2(e)
    const float KE  = 0.36787944f;          // e^-1

    // Unordered pairs (ordered histogram = 2x this; factor cancels in
    // count/total): slot p -> i = p>>8, k = (p&255)+1, j = (i+k) mod 512.
    // k==256 pairs appear for both endpoints; keep only i<256.
    const int total = NPTS * 256;           // 131072 slots, 2 per thread
    for (int p = blockIdx.x * TPB + tid; p < total; p += NBLK * TPB) {
        const int i = p >> 8;
        const int k = (p & 255) + 1;
        const bool valid = !(k == 256 && i >= 256);
        const int j = (i + k) & (NPTS - 1);
        float dx = fabsf(pos[3*i+0] - pos[3*j+0]);
        float dy = fabsf(pos[3*i+1] - pos[3*j+1]);
        float dz = fabsf(pos[3*i+2] - pos[3*j+2]);
        if (dx > RMAXF) dx = BOXF - dx;     // minimum-image fold
        if (dy > RMAXF) dy = BOXF - dy;
        if (dz > RMAXF) dz = BOXF - dz;
        const float dist = sqrtf(dx*dx + dy*dy + dz*dz);
        const float c = dist * inv_w;       // position in bin-width units
        float b0f = ceilf(c - 4.0f);        // +/-4 sigma window
        if (b0f < 0.0f) b0f = 0.0f;
        if (valid && dist > 0.0f && b0f <= 399.0f) {
            const int b0 = (int)b0f;
            const float u = c - b0f;        // u0 in [0, 4]
            float E = exp2f(C2E * u * u);
            float F = exp2f(C2F * (u - 0.5f));
            const int rmax = (NBINS - 1) - b0;
            #pragma unroll
            for (int r = 0; r < 9; ++r) {
                if (r <= rmax)
                    unsafeAtomicAdd(&hist[b0 + r], E);
                E *= F;
                F *= KE;
            }
        }
    }
    __syncthreads();
    for (int b = tid; b < NBINS; b += TPB)
        part[blockIdx.x * NBINS + b] = hist[b];
}

__global__ __launch_bounds__(512) void rdf_final(const float* __restrict__ part,
                                                 float* __restrict__ out) {
    __shared__ float ssum[8];
    const int t = threadIdx.x;

    float v = 0.0f;
    if (t < NBINS) {
        #pragma unroll 16
        for (int p = 0; p < NBLK; ++p) v += part[p * NBINS + t];
    }

    // total = sum over bins: wave(64) reduce then cross-wave via LDS
    float s = v;
    #pragma unroll
    for (int o = 32; o > 0; o >>= 1) s += __shfl_down(s, o, 64);
    if ((t & 63) == 0) ssum[t >> 6] = s;
    __syncthreads();
    if (t == 0) {
        float tot = 0.0f;
        #pragma unroll
        for (int w = 0; w < 8; ++w) tot += ssum[w];
        ssum[0] = tot;
    }
    __syncthreads();
    const float tot = ssum[0];

    if (t < NBINS) {
        const float cf = v / tot;
        out[t] = cf;                                   // count (normalized)
        // rdf = cf * V/vol_bin = cf * 400^3 / (3b^2+3b+1) (exact integer form)
        const float denom = (3.0f * t * t + 3.0f * t + 1.0f);
        out[801 + t] = cf * (400.0f * 400.0f * 400.0f) / denom;
    }
    if (t < NBINS + 1) {
        out[NBINS + t] = (float)t * (RMAXF / 400.0f);  // bins = linspace(0, R_MAX, 401)
    }
}

extern "C" void kernel_launch(void* const* d_in, const int* in_sizes, int n_in,
                              void* d_out, int out_size, void* d_ws, size_t ws_size,
                              hipStream_t stream) {
    const float* pos = (const float*)d_in[0];
    float* out = (float*)d_out;
    float* part = (float*)d_ws;   // NBLK*NBINS floats, fully overwritten each call

    rdf_hist<<<NBLK, TPB, 0, stream>>>(pos, part);
    rdf_final<<<1, 512, 0, stream>>>(part, out);
}